// Round 1
// baseline (1099.174 us; speedup 1.0000x reference)
//
#include <hip/hip_runtime.h>
#include <stdint.h>

// ---------------------------------------------------------------------------
// IsoMaxPlus distances: out[n,c] = -|scale| * sqrt(max(2 - 2*<f_n, p_c>, 1e-12))
//   1) row-normalize features  -> bf16 ws   [N=16384, D=2048]
//   2) row-normalize prototypes-> bf16 ws   [C=8192,  D=2048]
//   3) 256x256-tile 8-phase bf16 MFMA GEMM (B^T) + fused distance epilogue
// GEMM structure = m201 8-phase template: 8 waves (2Mx4N), BK=64, 128 KiB
// double-buffered LDS, XOR-swizzled LDS (T2), counted vmcnt(6) (T3+T4),
// setprio around MFMA clusters (T5), bijective XCD swizzle (T1).
// ---------------------------------------------------------------------------

#define K_DIM 2048
#define BM 256
#define BN 256
#define BK 64
#define NT (K_DIM / BK)  // 32 K-tiles

typedef short bf16x8 __attribute__((ext_vector_type(8)));
typedef float f32x4 __attribute__((ext_vector_type(4)));

__device__ __forceinline__ unsigned short f32_to_bf16(float f) {
  unsigned u = __float_as_uint(f);
  unsigned r = 0x7FFFu + ((u >> 16) & 1u);  // round-to-nearest-even
  return (unsigned short)((u + r) >> 16);
}

// one block per row, 256 threads, D = 2048 (8 floats/thread via 2x float4)
__global__ __launch_bounds__(256) void norm_rows_kernel(
    const float* __restrict__ in, unsigned short* __restrict__ out) {
  const int row = blockIdx.x;
  const int t = threadIdx.x;
  const float4* rp = (const float4*)(in + (size_t)row * K_DIM);
  float4 a = rp[t];
  float4 b = rp[t + 256];
  float ss = a.x * a.x + a.y * a.y + a.z * a.z + a.w * a.w +
             b.x * b.x + b.y * b.y + b.z * b.z + b.w * b.w;
#pragma unroll
  for (int off = 32; off > 0; off >>= 1) ss += __shfl_down(ss, off, 64);
  __shared__ float sred[4];
  if ((t & 63) == 0) sred[t >> 6] = ss;
  __syncthreads();
  float tot = sred[0] + sred[1] + sred[2] + sred[3];
  float inv = 1.0f / fmaxf(sqrtf(tot), 1e-12f);
  ushort4 oa, ob;
  oa.x = f32_to_bf16(a.x * inv);
  oa.y = f32_to_bf16(a.y * inv);
  oa.z = f32_to_bf16(a.z * inv);
  oa.w = f32_to_bf16(a.w * inv);
  ob.x = f32_to_bf16(b.x * inv);
  ob.y = f32_to_bf16(b.y * inv);
  ob.z = f32_to_bf16(b.z * inv);
  ob.w = f32_to_bf16(b.w * inv);
  ushort4* op = (ushort4*)(out + (size_t)row * K_DIM);
  op[t] = oa;
  op[t + 256] = ob;
}

// async 16B global -> LDS (wave-uniform LDS base; lane data lands at base+lane*16)
__device__ __forceinline__ void async_load16(const void* gptr, uint32_t lds_off,
                                             void* lds_base) {
  typedef __attribute__((address_space(3))) uint32_t lds_u32_t;
  typedef const __attribute__((address_space(1))) uint32_t glb_u32_t;
  glb_u32_t* g = reinterpret_cast<glb_u32_t*>(reinterpret_cast<uintptr_t>(gptr));
  lds_u32_t* l = reinterpret_cast<lds_u32_t*>(
      (uint32_t)(reinterpret_cast<uintptr_t>(lds_base) + lds_off));
  __builtin_amdgcn_global_load_lds(g, l, 16, 0, 0);
}

// --- staging helpers -------------------------------------------------------
// Half-tile = 128 rows x 64 cols bf16 = 16 KiB = 2 global_load_lds / thread.
// LDS is written LINEARLY by the DMA (dest = base + lane*16); the swizzle is
// applied by pre-swizzling the per-lane GLOBAL source column slot
// (slot ^= row&7), so physical LDS (row, slot) holds logical (row, slot^(row&7)).
__device__ __forceinline__ void stage_a(const unsigned short* gA,
                                        unsigned short* lds_, int wave, int buf,
                                        int half, int tt) {
  const unsigned short* s = gA + (size_t)(half * 128) * K_DIM + (size_t)tt * BK;
  uint32_t d = (uint32_t)(buf * 65536 + half * 16384 + wave * 1024);
  async_load16(s, d, lds_);
  async_load16(s + (size_t)64 * K_DIM, d + 8192u, lds_);
}
__device__ __forceinline__ void stage_b(const unsigned short* gB,
                                        unsigned short* lds_, int wave, int buf,
                                        int half, int tt) {
  const unsigned short* s = gB + (size_t)(half * 128) * K_DIM + (size_t)tt * BK;
  uint32_t d = (uint32_t)(buf * 65536 + 32768 + half * 16384 + wave * 1024);
  async_load16(s, d, lds_);
  async_load16(s + (size_t)64 * K_DIM, d + 8192u, lds_);
}

// --- fragment loads (swizzled ds_read_b128) --------------------------------
// logical 16B slot sl = ks*4 + (lane>>4); physical slot = sl ^ (lane&7)
//   -> element offset = ((((lane>>4) ^ (lane&7)) << 3) ^ (ks << 5))
__device__ __forceinline__ void ld_a(bf16x8 (&dst)[4][2],
                                     const unsigned short* lds_, int bufe,
                                     int mh, int wm, int frow, int lxe) {
#pragma unroll
  for (int fi = 0; fi < 4; ++fi)
#pragma unroll
    for (int ks = 0; ks < 2; ++ks)
      dst[fi][ks] = *(const bf16x8*)(lds_ + bufe +
                                     (wm * 128 + mh * 64 + fi * 16 + frow) * 64 +
                                     (lxe ^ (ks << 5)));
}
__device__ __forceinline__ void ld_b(bf16x8 (&dst)[2][2],
                                     const unsigned short* lds_, int bufe,
                                     int nh, int wn, int frow, int lxe) {
#pragma unroll
  for (int fj = 0; fj < 2; ++fj)
#pragma unroll
    for (int ks = 0; ks < 2; ++ks)
      dst[fj][ks] = *(const bf16x8*)(lds_ + bufe + 16384 +
                                     (wn * 64 + nh * 32 + fj * 16 + frow) * 64 +
                                     (lxe ^ (ks << 5)));
}

__device__ __forceinline__ void mfma_quad(f32x4 (&acc)[8][4],
                                          const bf16x8 (&af)[4][2],
                                          const bf16x8 (&bf)[2][2], int mh,
                                          int nh) {
#pragma unroll
  for (int fi = 0; fi < 4; ++fi)
#pragma unroll
    for (int fj = 0; fj < 2; ++fj) {
      f32x4 c = acc[mh * 4 + fi][nh * 2 + fj];
      c = __builtin_amdgcn_mfma_f32_16x16x32_bf16(af[fi][0], bf[fj][0], c, 0, 0, 0);
      c = __builtin_amdgcn_mfma_f32_16x16x32_bf16(af[fi][1], bf[fj][1], c, 0, 0, 0);
      acc[mh * 4 + fi][nh * 2 + fj] = c;
    }
}

// One K-tile = 4 phases; quadrant order (0,0)->(1,0)->(1,1)->(0,1).
// Region last-LDS-read: A0 ph1, B0 ph1, A1 ph2, B1 ph3.
// Stages (into cur buf only after region's reads completed + barrier):
//   ph1: T+1.B1 (other buf), ph2: T+2.A0, ph3: T+2.A1, ph4: T+2.B0.
// vmcnt(6) once per K-tile (= 3 half-tiles x 2 loads in flight).
#define KTILE(BUF, OBUF, T)                                                   \
  do {                                                                        \
    const int _stb1 = ((T) + 1 < NT) ? (T) + 1 : NT - 1;                      \
    const int _st2 = ((T) + 2 < NT) ? (T) + 2 : NT - 1;                       \
    /* phase 1 */                                                             \
    ld_a(a0, lds, (BUF)*32768, 0, wm, frow, lxe);                             \
    ld_b(b0, lds, (BUF)*32768, 0, wn, frow, lxe);                             \
    stage_b(gB, lds, wave, OBUF, 1, _stb1);                                   \
    __builtin_amdgcn_s_barrier();                                             \
    asm volatile("s_waitcnt lgkmcnt(0)" ::: "memory");                        \
    __builtin_amdgcn_s_setprio(1);                                            \
    mfma_quad(acc, a0, b0, 0, 0);                                             \
    __builtin_amdgcn_s_setprio(0);                                            \
    __builtin_amdgcn_s_barrier();                                             \
    /* phase 2 */                                                             \
    ld_a(a1, lds, (BUF)*32768, 1, wm, frow, lxe);                             \
    stage_a(gA, lds, wave, BUF, 0, _st2);                                     \
    __builtin_amdgcn_s_barrier();                                             \
    asm volatile("s_waitcnt lgkmcnt(0)" ::: "memory");                        \
    __builtin_amdgcn_s_setprio(1);                                            \
    mfma_quad(acc, a1, b0, 1, 0);                                             \
    __builtin_amdgcn_s_setprio(0);                                            \
    __builtin_amdgcn_s_barrier();                                             \
    /* phase 3 */                                                             \
    ld_b(b1, lds, (BUF)*32768, 1, wn, frow, lxe);                             \
    stage_a(gA, lds, wave, BUF, 1, _st2);                                     \
    __builtin_amdgcn_s_barrier();                                             \
    asm volatile("s_waitcnt lgkmcnt(0)" ::: "memory");                        \
    __builtin_amdgcn_s_setprio(1);                                            \
    mfma_quad(acc, a1, b1, 1, 1);                                             \
    __builtin_amdgcn_s_setprio(0);                                            \
    __builtin_amdgcn_s_barrier();                                             \
    /* phase 4 */                                                             \
    stage_b(gB, lds, wave, BUF, 0, _st2);                                     \
    asm volatile("s_waitcnt vmcnt(6)" ::: "memory");                          \
    __builtin_amdgcn_s_barrier();                                             \
    __builtin_amdgcn_s_setprio(1);                                            \
    mfma_quad(acc, a0, b1, 0, 1);                                             \
    __builtin_amdgcn_s_setprio(0);                                            \
    __builtin_amdgcn_s_barrier();                                             \
  } while (0)

__global__ __launch_bounds__(512, 2) void gemm_bt_dist(
    const unsigned short* __restrict__ A, const unsigned short* __restrict__ B,
    float* __restrict__ Out, const float* __restrict__ scale_ptr, int N,
    int C) {
  // [buf0.A 32K | buf0.B 32K | buf1.A 32K | buf1.B 32K] = 128 KiB
  __shared__ __align__(16) unsigned short lds[65536];

  const int tid = threadIdx.x;
  const int wave = tid >> 6;
  const int lane = tid & 63;
  const int wm = wave >> 2;  // 0..1 -> 128-row half
  const int wn = wave & 3;   // 0..3 -> 64-col slice

  // T1: bijective XCD swizzle (nwg = 2048, % 8 == 0); row-major tile order so
  // each XCD's ~32 concurrent blocks share one A panel (1 MiB, L2-resident).
  const int nwg = gridDim.x;
  const int orig = blockIdx.x;
  const int swz = (orig & 7) * (nwg >> 3) + (orig >> 3);
  const int tiles_n = C / BN;  // 32
  const int tm = swz / tiles_n;
  const int tn = swz % tiles_n;
  const int m0 = tm * BM;
  const int n0 = tn * BN;

  // staging source: pre-swizzled global column slot (rule #21: linear LDS dest
  // + inverse-swizzled source + swizzled read)
  const int srow = tid >> 3;                    // row within 64-row issue
  const int swslot = (tid & 7) ^ (srow & 7);    // 16B slot, pre-swizzled
  const unsigned short* gA = A + (size_t)(m0 + srow) * K_DIM + swslot * 8;
  const unsigned short* gB = B + (size_t)(n0 + srow) * K_DIM + swslot * 8;

  // fragment-read constants
  const int frow = lane & 15;
  const int lxe = (((lane >> 4) ^ (lane & 7)) << 3);  // swizzled elem offset

  f32x4 acc[8][4] = {};
  bf16x8 a0[4][2], a1[4][2], b0[2][2], b1[2][2];

  // prologue: stage T0 (4 halves) + T1.{A0,A1,B0}; wait T0 resident (6 in flight)
  stage_a(gA, lds, wave, 0, 0, 0);
  stage_a(gA, lds, wave, 0, 1, 0);
  stage_b(gB, lds, wave, 0, 0, 0);
  stage_b(gB, lds, wave, 0, 1, 0);
  stage_a(gA, lds, wave, 1, 0, 1);
  stage_a(gA, lds, wave, 1, 1, 1);
  stage_b(gB, lds, wave, 1, 0, 1);
  asm volatile("s_waitcnt vmcnt(6)" ::: "memory");
  __builtin_amdgcn_s_barrier();

#pragma unroll 1
  for (int t = 0; t < NT; t += 2) {
    KTILE(0, 1, t);
    KTILE(1, 0, t + 1);
  }

  // drain dummy tail stages before LDS goes away / epilogue
  asm volatile("s_waitcnt vmcnt(0)" ::: "memory");

  // epilogue: C/D layout col=lane&15, row=(lane>>4)*4+reg  [m89/m91]
  const float s = fabsf(scale_ptr[0]);
  const int ocol0 = n0 + wn * 64 + (lane & 15);
  const int orow0 = m0 + wm * 128 + ((lane >> 4) << 2);
#pragma unroll
  for (int ai = 0; ai < 8; ++ai) {
#pragma unroll
    for (int bj = 0; bj < 4; ++bj) {
      f32x4 v = acc[ai][bj];
#pragma unroll
      for (int r = 0; r < 4; ++r) {
        float sq = fmaxf(2.0f - 2.0f * v[r], 1e-12f);
        Out[(size_t)(orow0 + ai * 16 + r) * C + (ocol0 + bj * 16)] =
            -s * sqrtf(sq);
      }
    }
  }
}

extern "C" void kernel_launch(void* const* d_in, const int* in_sizes, int n_in,
                              void* d_out, int out_size, void* d_ws,
                              size_t ws_size, hipStream_t stream) {
  const float* feats = (const float*)d_in[0];   // [N, 2048] fp32
  const float* protos = (const float*)d_in[1];  // [C, 2048] fp32
  const float* dscale = (const float*)d_in[2];  // [1] fp32
  float* out = (float*)d_out;                   // [N, C] fp32

  const int N = in_sizes[0] / K_DIM;  // 16384
  const int C = in_sizes[1] / K_DIM;  // 8192

  unsigned short* fb = (unsigned short*)d_ws;    // [N][K] bf16
  unsigned short* pb = fb + (size_t)N * K_DIM;   // [C][K] bf16

  norm_rows_kernel<<<N, 256, 0, stream>>>(feats, fb);
  norm_rows_kernel<<<C, 256, 0, stream>>>(protos, pb);

  const int nwg = (N / BM) * (C / BN);  // 64 * 32 = 2048
  gemm_bt_dist<<<dim3(nwg), 512, 0, stream>>>(fb, pb, out, dscale, N, C);
}

// Round 4
// 1075.512 us; speedup vs baseline: 1.0220x; 1.0220x over previous
//
#include <hip/hip_runtime.h>
#include <stdint.h>

// ---------------------------------------------------------------------------
// IsoMaxPlus distances: out[n,c] = -|scale| * sqrt(max(2 - 2*<f_n, p_c>, 1e-12))
//   1) row-normalize features  -> bf16 ws   [N=16384, D=2048]  (wave-per-row)
//   2) row-normalize prototypes-> bf16 ws   [C=8192,  D=2048]  (wave-per-row)
//   3) 256x256-tile 8-phase bf16 MFMA GEMM (B^T) + fused distance epilogue
// GEMM structure = m201 8-phase template: 8 waves (2Mx4N), BK=64, 128 KiB
// double-buffered LDS, XOR-swizzled LDS (T2), counted vmcnt(6) (T3+T4),
// setprio around MFMA clusters (T5), XCD supertile swizzle (T1).
// ---------------------------------------------------------------------------

#define K_DIM 2048
#define BM 256
#define BN 256
#define BK 64
#define NT (K_DIM / BK)  // 32 K-tiles

typedef short bf16x8 __attribute__((ext_vector_type(8)));
typedef float f32x4 __attribute__((ext_vector_type(4)));

__device__ __forceinline__ unsigned short f32_to_bf16(float f) {
  unsigned u = __float_as_uint(f);
  unsigned r = 0x7FFFu + ((u >> 16) & 1u);  // round-to-nearest-even
  return (unsigned short)((u + r) >> 16);
}

// Wave-per-row L2 normalize + bf16 cast. Lane i holds float4 slots
// {i, i+64, ..., i+448} of the 512-float4 row -> 8 independent coalesced
// loads in flight per lane (no LDS, no __syncthreads; butterfly reduce).
__global__ __launch_bounds__(256) void norm_rows_wave(
    const float* __restrict__ in, unsigned short* __restrict__ out,
    int nrows) {
  const int lane = threadIdx.x & 63;
  const int wid = (blockIdx.x << 2) + (threadIdx.x >> 6);
  const int nw = gridDim.x << 2;
  for (int row = wid; row < nrows; row += nw) {
    const float4* rp = (const float4*)(in + (size_t)row * K_DIM);
    float4 v[8];
#pragma unroll
    for (int j = 0; j < 8; ++j) v[j] = rp[lane + (j << 6)];
    float ss = 0.0f;
#pragma unroll
    for (int j = 0; j < 8; ++j)
      ss += v[j].x * v[j].x + v[j].y * v[j].y + v[j].z * v[j].z +
            v[j].w * v[j].w;
#pragma unroll
    for (int off = 32; off > 0; off >>= 1) ss += __shfl_xor(ss, off, 64);
    const float inv = 1.0f / fmaxf(sqrtf(ss), 1e-12f);
    ushort4* op = (ushort4*)(out + (size_t)row * K_DIM);
#pragma unroll
    for (int j = 0; j < 8; ++j) {
      ushort4 o;
      o.x = f32_to_bf16(v[j].x * inv);
      o.y = f32_to_bf16(v[j].y * inv);
      o.z = f32_to_bf16(v[j].z * inv);
      o.w = f32_to_bf16(v[j].w * inv);
      op[lane + (j << 6)] = o;
    }
  }
}

// async 16B global -> LDS (wave-uniform LDS base; lane data lands at base+lane*16)
__device__ __forceinline__ void async_load16(const void* gptr, uint32_t lds_off,
                                             void* lds_base) {
  typedef __attribute__((address_space(3))) uint32_t lds_u32_t;
  typedef const __attribute__((address_space(1))) uint32_t glb_u32_t;
  glb_u32_t* g = reinterpret_cast<glb_u32_t*>(reinterpret_cast<uintptr_t>(gptr));
  lds_u32_t* l = reinterpret_cast<lds_u32_t*>(
      (uint32_t)(reinterpret_cast<uintptr_t>(lds_base) + lds_off));
  __builtin_amdgcn_global_load_lds(g, l, 16, 0, 0);
}

// --- staging helpers -------------------------------------------------------
// Half-tile = 128 rows x 64 cols bf16 = 16 KiB = 2 global_load_lds / thread.
// LDS is written LINEARLY by the DMA (dest = base + lane*16); the swizzle is
// applied by pre-swizzling the per-lane GLOBAL source column slot
// (slot ^= row&7), so physical LDS (row, slot) holds logical (row, slot^(row&7)).
__device__ __forceinline__ void stage_a(const unsigned short* gA,
                                        unsigned short* lds_, int wave, int buf,
                                        int half, int tt) {
  const unsigned short* s = gA + (size_t)(half * 128) * K_DIM + (size_t)tt * BK;
  uint32_t d = (uint32_t)(buf * 65536 + half * 16384 + wave * 1024);
  async_load16(s, d, lds_);
  async_load16(s + (size_t)64 * K_DIM, d + 8192u, lds_);
}
__device__ __forceinline__ void stage_b(const unsigned short* gB,
                                        unsigned short* lds_, int wave, int buf,
                                        int half, int tt) {
  const unsigned short* s = gB + (size_t)(half * 128) * K_DIM + (size_t)tt * BK;
  uint32_t d = (uint32_t)(buf * 65536 + 32768 + half * 16384 + wave * 1024);
  async_load16(s, d, lds_);
  async_load16(s + (size_t)64 * K_DIM, d + 8192u, lds_);
}

// --- fragment loads (swizzled ds_read_b128) --------------------------------
// logical 16B slot sl = ks*4 + (lane>>4); physical slot = sl ^ (lane&7)
//   -> element offset = ((((lane>>4) ^ (lane&7)) << 3) ^ (ks << 5))
__device__ __forceinline__ void ld_a(bf16x8 (&dst)[4][2],
                                     const unsigned short* lds_, int bufe,
                                     int mh, int wm, int frow, int lxe) {
#pragma unroll
  for (int fi = 0; fi < 4; ++fi)
#pragma unroll
    for (int ks = 0; ks < 2; ++ks)
      dst[fi][ks] = *(const bf16x8*)(lds_ + bufe +
                                     (wm * 128 + mh * 64 + fi * 16 + frow) * 64 +
                                     (lxe ^ (ks << 5)));
}
__device__ __forceinline__ void ld_b(bf16x8 (&dst)[2][2],
                                     const unsigned short* lds_, int bufe,
                                     int nh, int wn, int frow, int lxe) {
#pragma unroll
  for (int fj = 0; fj < 2; ++fj)
#pragma unroll
    for (int ks = 0; ks < 2; ++ks)
      dst[fj][ks] = *(const bf16x8*)(lds_ + bufe + 16384 +
                                     (wn * 64 + nh * 32 + fj * 16 + frow) * 64 +
                                     (lxe ^ (ks << 5)));
}

__device__ __forceinline__ void mfma_quad(f32x4 (&acc)[8][4],
                                          const bf16x8 (&af)[4][2],
                                          const bf16x8 (&bf)[2][2], int mh,
                                          int nh) {
#pragma unroll
  for (int fi = 0; fi < 4; ++fi)
#pragma unroll
    for (int fj = 0; fj < 2; ++fj) {
      f32x4 c = acc[mh * 4 + fi][nh * 2 + fj];
      c = __builtin_amdgcn_mfma_f32_16x16x32_bf16(af[fi][0], bf[fj][0], c, 0, 0, 0);
      c = __builtin_amdgcn_mfma_f32_16x16x32_bf16(af[fi][1], bf[fj][1], c, 0, 0, 0);
      acc[mh * 4 + fi][nh * 2 + fj] = c;
    }
}

// One K-tile = 4 phases; quadrant order (0,0)->(1,0)->(1,1)->(0,1).
// Region last-LDS-read: A0 ph1, B0 ph1, A1 ph2, B1 ph3.
// Stages (into cur buf only after region's reads completed + barrier):
//   ph1: T+1.B1 (other buf), ph2: T+2.A0, ph3: T+2.A1, ph4: T+2.B0.
// vmcnt(6) once per K-tile (= 3 half-tiles x 2 loads in flight).
#define KTILE(BUF, OBUF, T)                                                   \
  do {                                                                        \
    const int _stb1 = ((T) + 1 < NT) ? (T) + 1 : NT - 1;                      \
    const int _st2 = ((T) + 2 < NT) ? (T) + 2 : NT - 1;                       \
    /* phase 1 */                                                             \
    ld_a(a0, lds, (BUF)*32768, 0, wm, frow, lxe);                             \
    ld_b(b0, lds, (BUF)*32768, 0, wn, frow, lxe);                             \
    stage_b(gB, lds, wave, OBUF, 1, _stb1);                                   \
    __builtin_amdgcn_s_barrier();                                             \
    asm volatile("s_waitcnt lgkmcnt(0)" ::: "memory");                        \
    __builtin_amdgcn_s_setprio(1);                                            \
    mfma_quad(acc, a0, b0, 0, 0);                                             \
    __builtin_amdgcn_s_setprio(0);                                            \
    __builtin_amdgcn_s_barrier();                                             \
    /* phase 2 */                                                             \
    ld_a(a1, lds, (BUF)*32768, 1, wm, frow, lxe);                             \
    stage_a(gA, lds, wave, BUF, 0, _st2);                                     \
    __builtin_amdgcn_s_barrier();                                             \
    asm volatile("s_waitcnt lgkmcnt(0)" ::: "memory");                        \
    __builtin_amdgcn_s_setprio(1);                                            \
    mfma_quad(acc, a1, b0, 1, 0);                                             \
    __builtin_amdgcn_s_setprio(0);                                            \
    __builtin_amdgcn_s_barrier();                                             \
    /* phase 3 */                                                             \
    ld_b(b1, lds, (BUF)*32768, 1, wn, frow, lxe);                             \
    stage_a(gA, lds, wave, BUF, 1, _st2);                                     \
    __builtin_amdgcn_s_barrier();                                             \
    asm volatile("s_waitcnt lgkmcnt(0)" ::: "memory");                        \
    __builtin_amdgcn_s_setprio(1);                                            \
    mfma_quad(acc, a1, b1, 1, 1);                                             \
    __builtin_amdgcn_s_setprio(0);                                            \
    __builtin_amdgcn_s_barrier();                                             \
    /* phase 4 */                                                             \
    stage_b(gB, lds, wave, BUF, 0, _st2);                                     \
    asm volatile("s_waitcnt vmcnt(6)" ::: "memory");                          \
    __builtin_amdgcn_s_barrier();                                             \
    __builtin_amdgcn_s_setprio(1);                                            \
    mfma_quad(acc, a0, b1, 0, 1);                                             \
    __builtin_amdgcn_s_setprio(0);                                            \
    __builtin_amdgcn_s_barrier();                                             \
  } while (0)

__global__ __launch_bounds__(512, 2) void gemm_bt_dist(
    const unsigned short* __restrict__ A, const unsigned short* __restrict__ B,
    float* __restrict__ Out, const float* __restrict__ scale_ptr, int N,
    int C) {
  // [buf0.A 32K | buf0.B 32K | buf1.A 32K | buf1.B 32K] = 128 KiB
  __shared__ __align__(16) unsigned short lds[65536];

  const int tid = threadIdx.x;
  const int wave = tid >> 6;
  const int lane = tid & 63;
  const int wm = wave >> 2;  // 0..1 -> 128-row half
  const int wn = wave & 3;   // 0..3 -> 64-col slice

  // T1: XCD-aware swizzle. For the production shape (2048 blocks, 32 tile
  // cols) order each XCD's 256-block sequence as 4x8 supertiles so the ~32
  // concurrent blocks per XCD touch A 4MB + B 8MB instead of A 1MB + B 32MB.
  // Bijection: orig <-> (xcd=orig&7, l=orig>>3), l <-> (sc=l>>6, lm=(l&63)>>3,
  // ln=l&7); tm = xcd*8+lm, tn = sc*8+ln.
  const int nwg = gridDim.x;
  const int orig = blockIdx.x;
  const int tiles_n = C / BN;
  int tm, tn;
  if (nwg == 2048 && tiles_n == 32) {
    const int x = orig & 7;
    const int l = orig >> 3;
    tm = (x << 3) + ((l & 63) >> 3);
    tn = ((l >> 6) << 3) + (l & 7);
  } else {
    const int swz = (orig & 7) * (nwg >> 3) + (orig >> 3);
    tm = swz / tiles_n;
    tn = swz % tiles_n;
  }
  const int m0 = tm * BM;
  const int n0 = tn * BN;

  // staging source: pre-swizzled global column slot (rule #21: linear LDS dest
  // + inverse-swizzled source + swizzled read)
  const int srow = tid >> 3;                    // row within 64-row issue
  const int swslot = (tid & 7) ^ (srow & 7);    // 16B slot, pre-swizzled
  const unsigned short* gA = A + (size_t)(m0 + srow) * K_DIM + swslot * 8;
  const unsigned short* gB = B + (size_t)(n0 + srow) * K_DIM + swslot * 8;

  // fragment-read constants
  const int frow = lane & 15;
  const int lxe = (((lane >> 4) ^ (lane & 7)) << 3);  // swizzled elem offset

  f32x4 acc[8][4] = {};
  bf16x8 a0[4][2], a1[4][2], b0[2][2], b1[2][2];

  // prologue: stage T0 (4 halves) + T1.{A0,A1,B0}; wait T0 resident (6 in flight)
  stage_a(gA, lds, wave, 0, 0, 0);
  stage_a(gA, lds, wave, 0, 1, 0);
  stage_b(gB, lds, wave, 0, 0, 0);
  stage_b(gB, lds, wave, 0, 1, 0);
  stage_a(gA, lds, wave, 1, 0, 1);
  stage_a(gA, lds, wave, 1, 1, 1);
  stage_b(gB, lds, wave, 1, 0, 1);
  asm volatile("s_waitcnt vmcnt(6)" ::: "memory");
  __builtin_amdgcn_s_barrier();

#pragma unroll 1
  for (int t = 0; t < NT; t += 2) {
    KTILE(0, 1, t);
    KTILE(1, 0, t + 1);
  }

  // drain dummy tail stages before LDS goes away / epilogue
  asm volatile("s_waitcnt vmcnt(0)" ::: "memory");

  // epilogue: C/D layout col=lane&15, row=(lane>>4)*4+reg  [m89/m91]
  const float s = fabsf(scale_ptr[0]);
  const int ocol0 = n0 + wn * 64 + (lane & 15);
  const int orow0 = m0 + wm * 128 + ((lane >> 4) << 2);
#pragma unroll
  for (int ai = 0; ai < 8; ++ai) {
#pragma unroll
    for (int bj = 0; bj < 4; ++bj) {
      f32x4 v = acc[ai][bj];
#pragma unroll
      for (int r = 0; r < 4; ++r) {
        float sq = fmaxf(2.0f - 2.0f * v[r], 1e-12f);
        Out[(size_t)(orow0 + ai * 16 + r) * C + (ocol0 + bj * 16)] =
            -s * sqrtf(sq);
      }
    }
  }
}

extern "C" void kernel_launch(void* const* d_in, const int* in_sizes, int n_in,
                              void* d_out, int out_size, void* d_ws,
                              size_t ws_size, hipStream_t stream) {
  const float* feats = (const float*)d_in[0];   // [N, 2048] fp32
  const float* protos = (const float*)d_in[1];  // [C, 2048] fp32
  const float* dscale = (const float*)d_in[2];  // [1] fp32
  float* out = (float*)d_out;                   // [N, C] fp32

  const int N = in_sizes[0] / K_DIM;  // 16384
  const int C = in_sizes[1] / K_DIM;  // 8192

  unsigned short* fb = (unsigned short*)d_ws;    // [N][K] bf16
  unsigned short* pb = fb + (size_t)N * K_DIM;   // [C][K] bf16

  norm_rows_wave<<<2048, 256, 0, stream>>>(feats, fb, N);
  norm_rows_wave<<<2048, 256, 0, stream>>>(protos, pb, C);

  const int nwg = (N / BM) * (C / BN);  // 64 * 32 = 2048
  gemm_bt_dist<<<dim3(nwg), 512, 0, stream>>>(fb, pb, out, dscale, N, C);
}